// Round 7
// baseline (565.706 us; speedup 1.0000x reference)
//
#include <hip/hip_runtime.h>

// ---------------------------------------------------------------------------
// AttentionWithEinops: B=2,S=2048,D=2048,H=16,KVH=4,Dh=128, start_pos input.
// bf16 MFMA everywhere (fp32 accumulate), fp32 outputs.
// d_out = [output 2*2048*2048][k_cache 2*2048*4*128][v_cache 2*2048*4*128]
// ---------------------------------------------------------------------------

typedef __attribute__((ext_vector_type(8))) short frag8;   // 8 x bf16 (4 VGPR)
typedef __attribute__((ext_vector_type(4))) float facc4;   // 4 x f32 acc

#define DEVI __device__ __forceinline__

constexpr int Bc  = 2;
constexpr int Sc  = 2048;
constexpr int Dc  = 2048;
constexpr int Hc  = 16;
constexpr int KVHc = 4;
constexpr int Dhc = 128;
constexpr int Mc  = Bc * Sc;       // 4096
constexpr int NQc = Hc * Dhc;      // 2048
constexpr int NKVc = KVHc * Dhc;   // 512

DEVI unsigned short f2bf(float f) {
  union { float f; unsigned u; } v; v.f = f;
  return (unsigned short)((v.u + 0x7fffu + ((v.u >> 16) & 1u)) >> 16);
}
DEVI float bf2f(unsigned short h) {
  union { unsigned u; float f; } v; v.u = ((unsigned)h) << 16;
  return v.f;
}

DEVI void gload_lds16(const void* g, void* l) {
  __builtin_amdgcn_global_load_lds(
      (const __attribute__((address_space(1))) unsigned int*)g,
      (__attribute__((address_space(3))) unsigned int*)l, 16, 0, 0);
}

// DPP rotate-combine reduce over the 16-lane row (no LDS traffic).
DEVI float rowred_max(float x) {
  union { float f; int i; } a, b;
  a.f = x;
  b.i = __builtin_amdgcn_update_dpp(a.i, a.i, 0x128, 0xF, 0xF, false); a.f = fmaxf(a.f, b.f);
  b.i = __builtin_amdgcn_update_dpp(a.i, a.i, 0x124, 0xF, 0xF, false); a.f = fmaxf(a.f, b.f);
  b.i = __builtin_amdgcn_update_dpp(a.i, a.i, 0x122, 0xF, 0xF, false); a.f = fmaxf(a.f, b.f);
  b.i = __builtin_amdgcn_update_dpp(a.i, a.i, 0x121, 0xF, 0xF, false); a.f = fmaxf(a.f, b.f);
  return a.f;
}
DEVI float rowred_sum(float x) {
  union { float f; int i; } a, b;
  a.f = x;
  b.i = __builtin_amdgcn_update_dpp(a.i, a.i, 0x128, 0xF, 0xF, false); a.f += b.f;
  b.i = __builtin_amdgcn_update_dpp(a.i, a.i, 0x124, 0xF, 0xF, false); a.f += b.f;
  b.i = __builtin_amdgcn_update_dpp(a.i, a.i, 0x122, 0xF, 0xF, false); a.f += b.f;
  b.i = __builtin_amdgcn_update_dpp(a.i, a.i, 0x121, 0xF, 0xF, false); a.f += b.f;
  return a.f;
}

// ------------------- fused converters (one launch) -------------------------

__global__ void cvt_all(const float* __restrict__ residual,
                        const float* __restrict__ WQ,
                        const float* __restrict__ WK,
                        const float* __restrict__ WV,
                        const float* __restrict__ WO,
                        unsigned short* __restrict__ rb,
                        unsigned short* __restrict__ wqb,
                        unsigned short* __restrict__ wkvb,
                        unsigned short* __restrict__ wob) {
  __shared__ float tile[64][65];
  int bid = blockIdx.x;
  int t = threadIdx.x;
  if (bid < 14336) {
    const float* src; unsigned short* dst; int off;
    if (bid < 8192)       { src = residual; dst = rb;  off = bid; }
    else if (bid < 12288) { src = WQ; dst = wqb; off = bid - 8192; }
    else if (bid < 13312) { src = WK; dst = wkvb; off = bid - 12288; }
    else                  { src = WV; dst = wkvb + (size_t)NKVc * Dc; off = bid - 13312; }
    int i = (off * 256 + t) * 4;
    float4 v = *(const float4*)(src + i);
    ushort4 o;
    o.x = f2bf(v.x); o.y = f2bf(v.y); o.z = f2bf(v.z); o.w = f2bf(v.w);
    *(ushort4*)(dst + i) = o;
  } else {
    int tb = bid - 14336;
    int r0 = (tb >> 5) * 64;   // he base
    int c0 = (tb & 31) * 64;   // d base
#pragma unroll
    for (int i = 0; i < 16; ++i) {
      int idx = i * 256 + t; int r = idx >> 6, c = idx & 63;
      tile[r][c] = WO[(size_t)(r0 + r) * Dc + c0 + c];
    }
    __syncthreads();
#pragma unroll
    for (int i = 0; i < 16; ++i) {
      int idx = i * 256 + t; int r = idx >> 6, c = idx & 63;
      wob[(size_t)(c0 + r) * NQc + r0 + c] = f2bf(tile[c][r]);
    }
  }
}

// -- dbuf NT GEMM, BK=32, counted vmcnt, HIGH OCCUPANCY (5 blocks/CU cap) ---
// C[M,N] = A[M,K](bf16) * B[N,K](bf16)^T.
// BM=128, BN=128, BK=32; 256 thr = 4 waves (2M x 2N); per-wave 64x64 (acc 4x4).
// KEY FIX vs R6 (25% MfmaUtil, Occupancy ~13% ~= 1 block/CU): the 64 KB LDS
// capped residency at 2 blocks and delivered ~1 -> per-tile critical path
// (ds_read->lgkm->bar->MFMA->vmcnt->bar) ran unhidden (~3000 cyc/tile vs
// ~500 of pipe work). BK=32 halves LDS to 32 KB -> 5 blocks/CU cap (grid
// gives 3/CU QKV, 2/CU o-proj); co-resident blocks hide barrier/latency
// (m97's mechanism: 874 TF at 16KB/3 blocks with plain syncthreads).
// Counted-vmcnt depth-2 pipeline kept (R6: +13% over drain-0):
//   ds_read frags(buf p) x8 ; lgkmcnt(0) ; s_barrier
//   stage(t+2)->buf p (4 loads/thread)
//   MFMA x16
//   s_waitcnt vmcnt(4)  [t+1 landed; t+2 in flight] ; s_barrier
// Swizzle for BK=32: [row][4 chunks of 16B], chunk ^= (row&3); linear LDS
// dest + inverse-permuted global source + same XOR on ds_read (involution).
// Bank check: 16-lane group -> 2 lanes per 16B slot = 2-way = free (m136).
// XCD remap (T1): each XCD owns a contiguous band of n-panels.
// MODE 0: o-proj (f32 out).  MODE 1: fused QKV (q bf16 / k f32 / v f32+bf16^T).

DEVI void stage_tile(const unsigned short* A, const unsigned short* B,
                     unsigned short* Al, unsigned short* Bl,
                     int m0, int n0, int kt, int t, int Kk) {
#pragma unroll
  for (int i = 0; i < 2; ++i) {
    int c = i * 256 + t;                 // 512 chunks: 128 rows x 4 of 16B
    int row = c >> 2, ch = c & 3;
    int g = ch ^ (row & 3);              // inverse-permuted global chunk
    gload_lds16(A + (size_t)(m0 + row) * Kk + kt * 32 + g * 8, Al + c * 8);
  }
#pragma unroll
  for (int i = 0; i < 2; ++i) {
    int c = i * 256 + t;
    int row = c >> 2, ch = c & 3;
    int g = ch ^ (row & 3);
    gload_lds16(B + (size_t)(n0 + row) * Kk + kt * 32 + g * 8, Bl + c * 8);
  }
}

template <int MODE>
__global__ __launch_bounds__(256, 5) void gemm2b(
    const unsigned short* __restrict__ Amat,
    const unsigned short* __restrict__ Bmat,
    float* __restrict__ Cf, float* __restrict__ Cf2,
    unsigned short* __restrict__ Cb, unsigned short* __restrict__ Cb2,
    int Nn, int Kk) {
  __shared__ __align__(16) unsigned short As[2][128 * 32];
  __shared__ __align__(16) unsigned short Bs[2][128 * 32];

  int t = threadIdx.x;
  int lane = t & 63, w = t >> 6;
  int quad = lane >> 4, l16 = lane & 15;
  int l3 = l16 & 3;
  int wm = (w >> 1) * 64, wn = (w & 1) * 64;

  // XCD-aware remap: consecutive dispatch ids round-robin XCDs; give each
  // XCD a contiguous band of n-panels so B-panels are L2-resident per XCD.
  int lin = blockIdx.x + gridDim.x * blockIdx.y;
  int xcd = lin & 7, gg = lin >> 3;
  int ypx = gridDim.y >> 3;             // n-panels per XCD (3 QKV / 2 o-proj)
  int ny = xcd * ypx + (gg % ypx);
  int nx = gg / ypx;
  int m0 = nx * 128, n0 = ny * 128;
  const int NT = Kk >> 5;

  // swizzled ds_read offsets (ushort idx): row*32 + ((quad^(row&3))*8);
  // row&3 == l16&3 (wm, wn, mi*16, ni*16 are multiples of 4).
  auto aoff = [&](int mi) {
    return (wm + mi * 16 + l16) * 32 + ((quad ^ l3) * 8);
  };
  auto boff = [&](int ni) {
    return (wn + ni * 16 + l16) * 32 + ((quad ^ l3) * 8);
  };

  // prologue: stage tiles 0 and 1; wait tile 0 landed (tile 1's 4 in flight)
  stage_tile(Amat, Bmat, As[0], Bs[0], m0, n0, 0, t, Kk);
  if (NT > 1) stage_tile(Amat, Bmat, As[1], Bs[1], m0, n0, 1, t, Kk);
  if (NT > 1) asm volatile("s_waitcnt vmcnt(4)" ::: "memory");
  else        asm volatile("s_waitcnt vmcnt(0)" ::: "memory");
  __builtin_amdgcn_s_barrier();
  asm volatile("" ::: "memory");

  facc4 acc[4][4] = {};

  for (int kt = 0; kt < NT; ++kt) {
    const int p = kt & 1;
    const unsigned short* Ab = As[p];
    const unsigned short* Bb = Bs[p];
    frag8 aFr[4], bFr[4];
#pragma unroll
    for (int mi = 0; mi < 4; ++mi) aFr[mi] = *(const frag8*)&Ab[aoff(mi)];
#pragma unroll
    for (int ni = 0; ni < 4; ++ni) bFr[ni] = *(const frag8*)&Bb[boff(ni)];
    // reads of buf[p] complete before any wave overwrites it
    asm volatile("s_waitcnt lgkmcnt(0)" ::: "memory");
    __builtin_amdgcn_s_barrier();
    asm volatile("" ::: "memory");

    // stage tile kt+2 into buf[p] (just freed); 4 loads/thread in flight
    if (kt + 2 < NT)
      stage_tile(Amat, Bmat, As[p], Bs[p], m0, n0, kt + 2, t, Kk);

    __builtin_amdgcn_s_setprio(1);
#pragma unroll
    for (int mi = 0; mi < 4; ++mi)
#pragma unroll
      for (int ni = 0; ni < 4; ++ni)
        acc[mi][ni] = __builtin_amdgcn_mfma_f32_16x16x32_bf16(
            aFr[mi], bFr[ni], acc[mi][ni], 0, 0, 0);
    __builtin_amdgcn_s_setprio(0);

    // tile kt+1 landed (kt+2's 4 loads stay in flight); publish via barrier
    if (kt + 2 < NT) asm volatile("s_waitcnt vmcnt(4)" ::: "memory");
    else             asm volatile("s_waitcnt vmcnt(0)" ::: "memory");
    __builtin_amdgcn_s_barrier();
    asm volatile("" ::: "memory");
  }

  // ---- epilogue ----
#pragma unroll
  for (int mi = 0; mi < 4; ++mi)
#pragma unroll
    for (int ni = 0; ni < 4; ++ni)
#pragma unroll
      for (int i = 0; i < 4; ++i) {
        int row = m0 + wm + mi * 16 + quad * 4 + i;
        int col = n0 + wn + ni * 16 + l16;
        float v = acc[mi][ni][i];
        if (MODE == 0) {
          Cf[(size_t)row * Nn + col] = v;
        } else {
          if (col < NQc) {
            Cb[(size_t)row * NQc + col] = f2bf(v);             // q bf16
          } else if (col < NQc + NKVc) {
            Cf[(size_t)row * NKVc + (col - NQc)] = v;          // k f32
          } else {
            int nc = col - NQc - NKVc;
            Cf2[(size_t)row * NKVc + nc] = v;                  // v f32
            int b = row >> 11, s = row & (Sc - 1);
            Cb2[((size_t)(b * NKVc + nc)) * Sc + s] = f2bf(v); // v^T bf16
          }
        }
      }
}

// ---------------------------- fused RoPE -----------------------------------

__global__ void rope_all(unsigned short* qb, float* kf, unsigned short* kb,
                         const int* __restrict__ sp) {
  int idx = blockIdx.x * 256 + threadIdx.x;
  constexpr int NQ = Mc * Hc * 64;
  if (idx < NQ) {
    int e = idx & 63, h = (idx >> 6) & 15, m = idx >> 10;
    int s = m & (Sc - 1);
    float pos = (float)(sp[0] + s);
    float invf = exp2f(-(float)e * 0.20762050593046835f);
    float ang = pos * invf;
    float sn, cs; sincosf(ang, &sn, &cs);
    size_t base = (size_t)m * NQc + h * Dhc + e;
    float x1 = bf2f(qb[base]), x2 = bf2f(qb[base + 64]);
    qb[base]      = f2bf(x1 * cs - x2 * sn);
    qb[base + 64] = f2bf(x1 * sn + x2 * cs);
  } else {
    int j = idx - NQ;
    int e = j & 63, kvh = (j >> 6) & 3, m = j >> 8;
    int s = m & (Sc - 1);
    float pos = (float)(sp[0] + s);
    float invf = exp2f(-(float)e * 0.20762050593046835f);
    float ang = pos * invf;
    float sn, cs; sincosf(ang, &sn, &cs);
    size_t base = (size_t)m * NKVc + kvh * Dhc + e;
    float x1 = kf[base], x2 = kf[base + 64];
    float o1 = x1 * cs - x2 * sn;
    float o2 = x1 * sn + x2 * cs;
    kf[base] = o1; kf[base + 64] = o2;
    kb[base] = f2bf(o1); kb[base + 64] = f2bf(o2);
  }
}

// ---------------------- flash attention (bf16 MFMA) ------------------------
// (unchanged; frozen-reference softmax, diagonal-first)

DEVI void issue_tile(const unsigned short* kb, const unsigned short* vbT,
                     int bb, int kvh, int kt, int t,
                     unsigned short* KsB, unsigned short* VtB) {
#pragma unroll
  for (int i = 0; i < 4; ++i) {
    int c = i * 256 + t;
    int row = c >> 4, chp = c & 15;
    int ch = chp ^ (row & 15);
    gload_lds16(kb + (size_t)(bb * Sc + kt * 64 + row) * NKVc + kvh * Dhc + ch * 8,
                KsB + c * 8);
  }
#pragma unroll
  for (int i = 0; i < 4; ++i) {
    int c = i * 256 + t;
    int row = c >> 3, chp = c & 7;       // Vt: 128 rows x 8 chunks
    int ch = chp ^ (row & 7);
    gload_lds16(vbT + ((size_t)(bb * KVHc + kvh) * Dhc + row) * Sc + kt * 64 + ch * 8,
                VtB + c * 8);
  }
}

DEVI void load_q(frag8 (&aQc)[4], const unsigned short* qb, int bb, int qt,
                 int h, int w, int quad, int l16) {
  const unsigned short* qrow =
      qb + (size_t)(bb * Sc + qt * 64 + w * 16 + l16) * NQc + h * Dhc;
#pragma unroll
  for (int kd = 0; kd < 4; ++kd)
    aQc[kd] = *(const frag8*)(qrow + (kd * 4 + quad) * 8);
}

DEVI void write_o(unsigned short* qb, facc4 (&oacc)[8], float (&lrow)[4],
                  int bb, int qt, int h, int w, int quad, int l16) {
  float rinv[4];
#pragma unroll
  for (int i = 0; i < 4; ++i) rinv[i] = 1.0f / rowred_sum(lrow[i]);
#pragma unroll
  for (int c8 = 0; c8 < 8; ++c8)
#pragma unroll
    for (int i = 0; i < 4; ++i) {
      int row = qt * 64 + w * 16 + quad * 4 + i;
      size_t o = ((size_t)(bb * Sc + row) * Hc + h) * Dhc + c8 * 16 + l16;
      qb[o] = f2bf(oacc[c8][i] * rinv[i]);
    }
}

__global__ __launch_bounds__(256, 2) void flash_attn(
    unsigned short* qb,                      // [M][H][Dh] bf16, in+out
    const unsigned short* __restrict__ kb,   // [M][KVH][Dh] bf16 (roped)
    const unsigned short* __restrict__ vbT,  // [B][KVH][Dh][S] bf16
    const int* __restrict__ spp) {
  __shared__ __align__(16) unsigned short Ks[2][64 * 128];
  __shared__ __align__(16) unsigned short Vt[2][128 * 64];
  __shared__ __align__(16) unsigned short Ps[4][16 * 64];

  int g = blockIdx.x & 7;
  int bb = g >> 2, kvh = g & 3;
  int inner = blockIdx.x >> 3;
  int pair = inner & 15, hh = inner >> 4;
  int h = kvh * 4 + hh;
  int qtA = pair, qtB = 31 - pair;

  int t = threadIdx.x, lane = t & 63, w = t >> 6;
  int quad = lane >> 4, l16 = lane & 15;
  int sp = spp[0];
  constexpr float LOG2E = 1.4426950408889634f;
  const float SC = 0.08838834764831845f * LOG2E;
  float slope2 = exp2f(-0.5f * (float)(h + 1)) * LOG2E;
  float s2x16 = slope2 * 16.0f;
  float s2x64 = slope2 * 64.0f;

  int tA = min((sp + qtA * 64 + 63) >> 6, 31) + 1;
  int tB = min((sp + qtB * 64 + 63) >> 6, 31) + 1;
  int total = tA + tB;

  frag8 aQc[4];
  load_q(aQc, qb, bb, qtA, h, w, quad, l16);

  facc4 oacc[8] = {};
  float mrow[4], lrow[4], bq[4], adn[4][4];
  int qposi[4];
  int qt = qtA;
#pragma unroll
  for (int i = 0; i < 4; ++i) {
    mrow[i] = -1e30f; lrow[i] = 0.f;
    qposi[i] = sp + qt * 64 + w * 16 + quad * 4 + i;
    bq[i] = slope2 * (float)qposi[i];
  }

  issue_tile(kb, vbT, bb, kvh, tA - 1, t, Ks[0], Vt[0]);

  for (int it = 0; it < total; ++it) {
    if (it == tA) {
      write_o(qb, oacc, lrow, bb, qtA, h, w, quad, l16);
      load_q(aQc, qb, bb, qtB, h, w, quad, l16);
      qt = qtB;
#pragma unroll
      for (int c8 = 0; c8 < 8; ++c8)
#pragma unroll
        for (int i = 0; i < 4; ++i) oacc[c8][i] = 0.f;
#pragma unroll
      for (int i = 0; i < 4; ++i) {
        mrow[i] = -1e30f; lrow[i] = 0.f;
        qposi[i] = sp + qt * 64 + w * 16 + quad * 4 + i;
        bq[i] = slope2 * (float)qposi[i];
      }
    }
    int kt = (it < tA) ? (tA - 1 - it) : (total - 1 - it);
    bool first = (it == 0) || (it == tA);

    if (it + 1 < total) {
      int nk = (it + 1 < tA) ? (tA - 2 - it) : (total - 2 - it);
      issue_tile(kb, vbT, bb, kvh, nk, t, Ks[(it + 1) & 1], Vt[(it + 1) & 1]);
      asm volatile("s_waitcnt vmcnt(8)" ::: "memory");
    } else {
      asm volatile("s_waitcnt vmcnt(0)" ::: "memory");
    }
    __builtin_amdgcn_s_barrier();
    asm volatile("" ::: "memory");

    const unsigned short* KsB = Ks[it & 1];
    const unsigned short* VtB = Vt[it & 1];

    facc4 sacc[4] = {};
#pragma unroll
    for (int kd = 0; kd < 4; ++kd) {
      int ch = kd * 4 + quad;
#pragma unroll
      for (int c4 = 0; c4 < 4; ++c4) {
        frag8 bK = *(const frag8*)&KsB[(c4 * 16 + l16) * 128 + (ch ^ l16) * 8];
        sacc[c4] = __builtin_amdgcn_mfma_f32_16x16x32_bf16(aQc[kd], bK, sacc[c4], 0, 0, 0);
      }
    }

    unsigned short* Pw = &Ps[w][0];
    int r0 = quad * 4;
    bool needmask = (kt * 64 + 63) > (sp + qt * 64);

    if (first || needmask) {
      float sv[4][4];
      float mt[4] = {-1e30f, -1e30f, -1e30f, -1e30f};
#pragma unroll
      for (int c4 = 0; c4 < 4; ++c4) {
        int kpos = kt * 64 + c4 * 16 + l16;
        float bk = slope2 * (float)kpos;
#pragma unroll
        for (int i = 0; i < 4; ++i) {
          float v = fmaf(sacc[c4][i], SC, bk - bq[i]);
          if (needmask) v = (kpos <= qposi[i]) ? v : -1e30f;
          sv[c4][i] = v;
          mt[i] = fmaxf(mt[i], v);
        }
      }
#pragma unroll
      for (int i = 0; i < 4; ++i) mt[i] = rowred_max(mt[i]);
#pragma unroll
      for (int i = 0; i < 4; ++i) {
        float mn = fmaxf(mrow[i], mt[i]);
        float alpha = exp2f(mrow[i] - mn);
        mrow[i] = mn;
        lrow[i] *= alpha;
#pragma unroll
        for (int c8 = 0; c8 < 8; ++c8) oacc[c8][i] *= alpha;
      }
#pragma unroll
      for (int c4 = 0; c4 < 4; ++c4) {
        float p0 = exp2f(sv[c4][0] - mrow[0]);
        float p1 = exp2f(sv[c4][1] - mrow[1]);
        float p2 = exp2f(sv[c4][2] - mrow[2]);
        float p3 = exp2f(sv[c4][3] - mrow[3]);
        lrow[0] += p0; lrow[1] += p1; lrow[2] += p2; lrow[3] += p3;
        unsigned u01, u23;
        asm("v_cvt_pk_bf16_f32 %0, %1, %2" : "=v"(u01) : "v"(p0), "v"(p1));
        asm("v_cvt_pk_bf16_f32 %0, %1, %2" : "=v"(u23) : "v"(p2), "v"(p3));
        int kk = c4 * 16 + l16;
        int col = kk & 7, chnk = kk >> 3;
        Pw[(r0 + 0) * 64 + ((chnk ^ ((r0 + 0) & 7)) * 8) + col] = (unsigned short)(u01 & 0xffffu);
        Pw[(r0 + 1) * 64 + ((chnk ^ ((r0 + 1) & 7)) * 8) + col] = (unsigned short)(u01 >> 16);
        Pw[(r0 + 2) * 64 + ((chnk ^ ((r0 + 2) & 7)) * 8) + col] = (unsigned short)(u23 & 0xffffu);
        Pw[(r0 + 3) * 64 + ((chnk ^ ((r0 + 3) & 7)) * 8) + col] = (unsigned short)(u23 >> 16);
      }
      float bkn0 = slope2 * (float)((kt - 1) * 64 + l16);
#pragma unroll
      for (int c4 = 0; c4 < 4; ++c4) {
        float bkc = bkn0 + (float)c4 * s2x16;
#pragma unroll
        for (int i = 0; i < 4; ++i) adn[c4][i] = bkc - bq[i] - mrow[i];
      }
    } else {
#pragma unroll
      for (int c4 = 0; c4 < 4; ++c4) {
        float p0 = exp2f(fmaf(sacc[c4][0], SC, adn[c4][0]));
        float p1 = exp2f(fmaf(sacc[c4][1], SC, adn[c4][1]));
        float p2 = exp2f(fmaf(sacc[c4][2], SC, adn[c4][2]));
        float p3 = exp2f(fmaf(sacc[c4][3], SC, adn[c4][3]));
        lrow[0] += p0; lrow[1] += p1; lrow[2] += p2; lrow[3] += p3;
        adn[c4][0] -= s2x64; adn[c4][1] -= s2x64;
        adn[c4][2] -= s2x64; adn[c4][3] -= s2x64;
        unsigned u01, u23;
        asm("v_cvt_pk_bf16_f32 %0, %1, %2" : "=v"(u01) : "v"(p0), "v"(p1));
        asm("v_cvt_pk_bf16_f32 %0, %1, %2" : "=v"(u23) : "v"(p2), "v"(p3));
        int kk = c4 * 16 + l16;
        int col = kk & 7, chnk = kk >> 3;
        Pw[(r0 + 0) * 64 + ((chnk ^ ((r0 + 0) & 7)) * 8) + col] = (unsigned short)(u01 & 0xffffu);
        Pw[(r0 + 1) * 64 + ((chnk ^ ((r0 + 1) & 7)) * 8) + col] = (unsigned short)(u01 >> 16);
        Pw[(r0 + 2) * 64 + ((chnk ^ ((r0 + 2) & 7)) * 8) + col] = (unsigned short)(u23 & 0xffffu);
        Pw[(r0 + 3) * 64 + ((chnk ^ ((r0 + 3) & 7)) * 8) + col] = (unsigned short)(u23 >> 16);
      }
    }

#pragma unroll
    for (int k2 = 0; k2 < 2; ++k2) {
      int ch = k2 * 4 + quad;
      frag8 aP = *(const frag8*)&Ps[w][l16 * 64 + (ch ^ (l16 & 7)) * 8];
#pragma unroll
      for (int c8 = 0; c8 < 8; ++c8) {
        frag8 bV = *(const frag8*)&VtB[(c8 * 16 + l16) * 64 + (ch ^ (l16 & 7)) * 8];
        oacc[c8] = __builtin_amdgcn_mfma_f32_16x16x32_bf16(aP, bV, oacc[c8], 0, 0, 0);
      }
    }

    if (!first) {
      int ovf = (lrow[0] > 16777216.f) || (lrow[1] > 16777216.f) ||
                (lrow[2] > 16777216.f) || (lrow[3] > 16777216.f);
      if (__any(ovf)) {
        const float DS = 0x1p-32f;
#pragma unroll
        for (int i = 0; i < 4; ++i) { lrow[i] *= DS; mrow[i] += 32.f; }
#pragma unroll
        for (int c4 = 0; c4 < 4; ++c4)
#pragma unroll
          for (int i = 0; i < 4; ++i) adn[c4][i] -= 32.f;
#pragma unroll
        for (int c8 = 0; c8 < 8; ++c8)
#pragma unroll
          for (int i = 0; i < 4; ++i) oacc[c8][i] *= DS;
      }
    }

    asm volatile("" ::: "memory");
    __builtin_amdgcn_s_barrier();
  }

  write_o(qb, oacc, lrow, bb, qtB, h, w, quad, l16);
}

// ------------------------------- launcher ----------------------------------

extern "C" void kernel_launch(void* const* d_in, const int* in_sizes, int n_in,
                              void* d_out, int out_size, void* d_ws, size_t ws_size,
                              hipStream_t stream) {
  const float* residual = (const float*)d_in[0];
  const float* W_Q = (const float*)d_in[1];
  const float* W_K = (const float*)d_in[2];
  const float* W_V = (const float*)d_in[3];
  const float* W_O = (const float*)d_in[4];
  const int* start_pos = (const int*)d_in[5];

  float* out = (float*)d_out;                        // [2][2048][2048]
  float* kf = out + (size_t)Bc * Sc * Dc;            // [4096][512] fp32 k cache
  float* vf = kf + (size_t)Mc * NKVc;                // [4096][512] fp32 v cache

  char* w = (char*)d_ws;
  auto alloc = [&](size_t bytes) {
    char* p = w; w += (bytes + 255) & ~(size_t)255; return p;
  };
  unsigned short* rb   = (unsigned short*)alloc((size_t)Mc * Dc * 2);
  unsigned short* wqkv = (unsigned short*)alloc((size_t)(NQc + 2 * NKVc) * Dc * 2); // [Q;K;V] rows
  unsigned short* wob  = (unsigned short*)alloc((size_t)Dc * NQc * 2);
  unsigned short* qb   = (unsigned short*)alloc((size_t)Mc * NQc * 2);
  unsigned short* kb   = (unsigned short*)alloc((size_t)Mc * NKVc * 2);
  unsigned short* vbT  = (unsigned short*)alloc((size_t)Mc * NKVc * 2);
  (void)ws_size; (void)in_sizes; (void)n_in; (void)out_size;

  // one fused converter launch; W_K/W_V land contiguously after W_Q rows
  cvt_all<<<15360, 256, 0, stream>>>(residual, W_Q, W_K, W_V, W_O,
                                     rb, wqkv, wqkv + (size_t)NQc * Dc, wob);

  // fused QKV projection: N = 2048(Q) + 512(K) + 512(V) = 3072
  gemm2b<1><<<dim3(32, 24), 256, 0, stream>>>(rb, wqkv, kf, vf, qb, vbT,
                                              NQc + 2 * NKVc, Dc);

  // fused RoPE (q + k)
  rope_all<<<20480, 256, 0, stream>>>(qb, kf, kb, start_pos);

  flash_attn<<<512, 256, 0, stream>>>(qb, kb, vbT, start_pos);

  // output projection: attn (in qb) x W_O^T -> d_out
  gemm2b<0><<<dim3(32, 16), 256, 0, stream>>>(qb, wob, out, nullptr, nullptr,
                                              nullptr, Dc, Dc);
}

// Round 8
// 328.513 us; speedup vs baseline: 1.7220x; 1.7220x over previous
//
#include <hip/hip_runtime.h>

// ---------------------------------------------------------------------------
// AttentionWithEinops: B=2,S=2048,D=2048,H=16,KVH=4,Dh=128, start_pos input.
// bf16 MFMA everywhere (fp32 accumulate), fp32 outputs.
// d_out = [output 2*2048*2048][k_cache 2*2048*4*128][v_cache 2*2048*4*128]
// ---------------------------------------------------------------------------

typedef __attribute__((ext_vector_type(8))) short frag8;   // 8 x bf16 (4 VGPR)
typedef __attribute__((ext_vector_type(4))) float facc4;   // 4 x f32 acc

#define DEVI __device__ __forceinline__

constexpr int Bc  = 2;
constexpr int Sc  = 2048;
constexpr int Dc  = 2048;
constexpr int Hc  = 16;
constexpr int KVHc = 4;
constexpr int Dhc = 128;
constexpr int Mc  = Bc * Sc;       // 4096
constexpr int NQc = Hc * Dhc;      // 2048
constexpr int NKVc = KVHc * Dhc;   // 512

DEVI unsigned short f2bf(float f) {
  union { float f; unsigned u; } v; v.f = f;
  return (unsigned short)((v.u + 0x7fffu + ((v.u >> 16) & 1u)) >> 16);
}
DEVI float bf2f(unsigned short h) {
  union { unsigned u; float f; } v; v.u = ((unsigned)h) << 16;
  return v.f;
}

DEVI void gload_lds16(const void* g, void* l) {
  __builtin_amdgcn_global_load_lds(
      (const __attribute__((address_space(1))) unsigned int*)g,
      (__attribute__((address_space(3))) unsigned int*)l, 16, 0, 0);
}

// DPP rotate-combine reduce over the 16-lane row (no LDS traffic).
DEVI float rowred_max(float x) {
  union { float f; int i; } a, b;
  a.f = x;
  b.i = __builtin_amdgcn_update_dpp(a.i, a.i, 0x128, 0xF, 0xF, false); a.f = fmaxf(a.f, b.f);
  b.i = __builtin_amdgcn_update_dpp(a.i, a.i, 0x124, 0xF, 0xF, false); a.f = fmaxf(a.f, b.f);
  b.i = __builtin_amdgcn_update_dpp(a.i, a.i, 0x122, 0xF, 0xF, false); a.f = fmaxf(a.f, b.f);
  b.i = __builtin_amdgcn_update_dpp(a.i, a.i, 0x121, 0xF, 0xF, false); a.f = fmaxf(a.f, b.f);
  return a.f;
}
DEVI float rowred_sum(float x) {
  union { float f; int i; } a, b;
  a.f = x;
  b.i = __builtin_amdgcn_update_dpp(a.i, a.i, 0x128, 0xF, 0xF, false); a.f += b.f;
  b.i = __builtin_amdgcn_update_dpp(a.i, a.i, 0x124, 0xF, 0xF, false); a.f += b.f;
  b.i = __builtin_amdgcn_update_dpp(a.i, a.i, 0x122, 0xF, 0xF, false); a.f += b.f;
  b.i = __builtin_amdgcn_update_dpp(a.i, a.i, 0x121, 0xF, 0xF, false); a.f += b.f;
  return a.f;
}

// ------------------- fused converters + RoPE table (one launch) ------------
// blocks [0,8192)        : residual f32->bf16
// blocks [8192,12288)    : W_Q
// blocks [12288,13312)   : W_K
// blocks [13312,14336)   : W_V
// blocks [14336,15360)   : W_O transpose
// blocks [15360,15872)   : RoPE cos/sin table: tab[s*64+e] = {cos,sin} of
//                          (sp+s) * base^(-e/64); 131K sincos once here vs
//                          6.3M scalar sincosf in the old rope kernel.

__global__ void cvt_all(const float* __restrict__ residual,
                        const float* __restrict__ WQ,
                        const float* __restrict__ WK,
                        const float* __restrict__ WV,
                        const float* __restrict__ WO,
                        unsigned short* __restrict__ rb,
                        unsigned short* __restrict__ wqb,
                        unsigned short* __restrict__ wkvb,
                        unsigned short* __restrict__ wob,
                        float2* __restrict__ tab,
                        const int* __restrict__ sp) {
  __shared__ float tile[64][65];
  int bid = blockIdx.x;
  int t = threadIdx.x;
  if (bid < 14336) {
    const float* src; unsigned short* dst; int off;
    if (bid < 8192)       { src = residual; dst = rb;  off = bid; }
    else if (bid < 12288) { src = WQ; dst = wqb; off = bid - 8192; }
    else if (bid < 13312) { src = WK; dst = wkvb; off = bid - 12288; }
    else                  { src = WV; dst = wkvb + (size_t)NKVc * Dc; off = bid - 13312; }
    int i = (off * 256 + t) * 4;
    float4 v = *(const float4*)(src + i);
    ushort4 o;
    o.x = f2bf(v.x); o.y = f2bf(v.y); o.z = f2bf(v.z); o.w = f2bf(v.w);
    *(ushort4*)(dst + i) = o;
  } else if (bid < 15360) {
    int tb = bid - 14336;
    int r0 = (tb >> 5) * 64;   // he base
    int c0 = (tb & 31) * 64;   // d base
#pragma unroll
    for (int i = 0; i < 16; ++i) {
      int idx = i * 256 + t; int r = idx >> 6, c = idx & 63;
      tile[r][c] = WO[(size_t)(r0 + r) * Dc + c0 + c];
    }
    __syncthreads();
#pragma unroll
    for (int i = 0; i < 16; ++i) {
      int idx = i * 256 + t; int r = idx >> 6, c = idx & 63;
      wob[(size_t)(c0 + r) * NQc + r0 + c] = f2bf(tile[c][r]);
    }
  } else {
    int idx = (bid - 15360) * 256 + t;   // 131072 (s,e) entries
    int s = idx >> 6, e = idx & 63;
    float ang = (float)(sp[0] + s) * exp2f(-(float)e * 0.20762050593046835f);
    float sn, cs; sincosf(ang, &sn, &cs);
    tab[idx] = make_float2(cs, sn);
  }
}

// ----- double-buffered NT GEMM, counted vmcnt (depth-2 pipeline, T4) -------
// C[M,N] = A[M,K](bf16) * B[N,K](bf16)^T.
// BM=128, BN=128, BK=64; 256 thr = 4 waves (2M x 2N); per-wave 64x64 (acc 4x4).
// LDS 64 KB double-buffered. R6 structure (82 us, best measured) with ONE
// reorder: MFMAs issue directly after the frag ds_reads (compiler inserts
// fine-grained lgkmcnt(4/3/1/0), m97-style interleave) instead of a full
// lgkmcnt(0) drain before the matrix work. Buffer-free fence (lgkm0+barrier)
// moved AFTER the MFMA cluster; stage(t+2) then fills the freed buffer and
// waits vmcnt(8) = tile t+1 landed, t+2 in flight. Never vmcnt(0) mid-loop.
// R7 lessons kept OUT: no high min-occupancy launch_bounds (VGPR 48 ->
// accumulator scratch-spill, 400 MB writes); no BK=32 (64 B rows only have
// 4 chunk positions -> unavoidable 4-way LDS conflicts).
// Swizzle (0 conflicts, R4-R6): [row][8 chunks of 16B], chunk ^= (row&7);
// linear LDS dest + inverse-permuted global source + same XOR on ds_read.
// XCD remap (T1): each XCD owns a contiguous band of n-panels.
// MODE 0: o-proj (f32 out).  MODE 1: fused QKV (q bf16 / k f32 / v f32+bf16^T).

DEVI void stage_tile(const unsigned short* A, const unsigned short* B,
                     unsigned short* Al, unsigned short* Bl,
                     int m0, int n0, int kt, int t, int Kk) {
#pragma unroll
  for (int i = 0; i < 4; ++i) {
    int c = i * 256 + t;                 // 1024 chunks: 128 rows x 8 of 16B
    int row = c >> 3, ch = c & 7;
    int g = ch ^ (row & 7);              // inverse-permuted global chunk
    gload_lds16(A + (size_t)(m0 + row) * Kk + kt * 64 + g * 8, Al + c * 8);
  }
#pragma unroll
  for (int i = 0; i < 4; ++i) {
    int c = i * 256 + t;
    int row = c >> 3, ch = c & 7;
    int g = ch ^ (row & 7);
    gload_lds16(B + (size_t)(n0 + row) * Kk + kt * 64 + g * 8, Bl + c * 8);
  }
}

template <int MODE>
__global__ __launch_bounds__(256, 2) void gemm2b(
    const unsigned short* __restrict__ Amat,
    const unsigned short* __restrict__ Bmat,
    float* __restrict__ Cf, float* __restrict__ Cf2,
    unsigned short* __restrict__ Cb, unsigned short* __restrict__ Cb2,
    int Nn, int Kk) {
  __shared__ __align__(16) unsigned short As[2][128 * 64];
  __shared__ __align__(16) unsigned short Bs[2][128 * 64];

  int t = threadIdx.x;
  int lane = t & 63, w = t >> 6;
  int quad = lane >> 4, l16 = lane & 15;
  int l7 = l16 & 7;
  int wm = (w >> 1) * 64, wn = (w & 1) * 64;

  // XCD-aware remap: consecutive dispatch ids round-robin XCDs; give each
  // XCD a contiguous band of n-panels so B-panels are L2-resident per XCD.
  int lin = blockIdx.x + gridDim.x * blockIdx.y;
  int xcd = lin & 7, gg = lin >> 3;
  int ypx = gridDim.y >> 3;             // n-panels per XCD (3 QKV / 2 o-proj)
  int ny = xcd * ypx + (gg % ypx);
  int nx = gg / ypx;
  int m0 = nx * 128, n0 = ny * 128;
  const int NT = Kk >> 6;

  // swizzled ds_read offsets (ushort idx): row*64 + ((ks*4+quad)^(row&7))*8;
  // row&7 == l16&7 (wm, wn, mi*16, ni*16 are multiples of 16).
  auto aoff = [&](int mi, int ks) {
    return (wm + mi * 16 + l16) * 64 + (((ks * 4 + quad) ^ l7) * 8);
  };
  auto boff = [&](int ni, int ks) {
    return (wn + ni * 16 + l16) * 64 + (((ks * 4 + quad) ^ l7) * 8);
  };

  // prologue: stage tiles 0 and 1; wait tile 0 landed (tile 1's 8 in flight)
  stage_tile(Amat, Bmat, As[0], Bs[0], m0, n0, 0, t, Kk);
  if (NT > 1) stage_tile(Amat, Bmat, As[1], Bs[1], m0, n0, 1, t, Kk);
  if (NT > 1) asm volatile("s_waitcnt vmcnt(8)" ::: "memory");
  else        asm volatile("s_waitcnt vmcnt(0)" ::: "memory");
  __builtin_amdgcn_s_barrier();
  asm volatile("" ::: "memory");

  facc4 acc[4][4] = {};

  for (int kt = 0; kt < NT; ++kt) {
    const int p = kt & 1;
    const unsigned short* Ab = As[p];
    const unsigned short* Bb = Bs[p];
    frag8 aFr[4][2], bFr[4][2];
#pragma unroll
    for (int ks = 0; ks < 2; ++ks) {
#pragma unroll
      for (int mi = 0; mi < 4; ++mi) aFr[mi][ks] = *(const frag8*)&Ab[aoff(mi, ks)];
#pragma unroll
      for (int ni = 0; ni < 4; ++ni) bFr[ni][ks] = *(const frag8*)&Bb[boff(ni, ks)];
    }

    // MFMAs start as soon as their frags arrive (compiler fine-grained
    // lgkmcnt) — no full LDS drain before matrix work.
    __builtin_amdgcn_s_setprio(1);
#pragma unroll
    for (int ks = 0; ks < 2; ++ks)
#pragma unroll
      for (int mi = 0; mi < 4; ++mi)
#pragma unroll
        for (int ni = 0; ni < 4; ++ni)
          acc[mi][ni] = __builtin_amdgcn_mfma_f32_16x16x32_bf16(
              aFr[mi][ks], bFr[ni][ks], acc[mi][ni], 0, 0, 0);
    __builtin_amdgcn_s_setprio(0);

    // all reads of buf p complete (consumed by MFMA); fence + free buffer
    asm volatile("s_waitcnt lgkmcnt(0)" ::: "memory");
    __builtin_amdgcn_s_barrier();
    asm volatile("" ::: "memory");

    // stage tile kt+2 into buf p (just freed); 8 loads/thread
    if (kt + 2 < NT) {
      stage_tile(Amat, Bmat, As[p], Bs[p], m0, n0, kt + 2, t, Kk);
      asm volatile("s_waitcnt vmcnt(8)" ::: "memory");  // t+1 landed; t+2 in flight
    } else {
      asm volatile("s_waitcnt vmcnt(0)" ::: "memory");  // tail drain
    }
    __builtin_amdgcn_s_barrier();
    asm volatile("" ::: "memory");
  }

  // ---- epilogue ----
#pragma unroll
  for (int mi = 0; mi < 4; ++mi)
#pragma unroll
    for (int ni = 0; ni < 4; ++ni)
#pragma unroll
      for (int i = 0; i < 4; ++i) {
        int row = m0 + wm + mi * 16 + quad * 4 + i;
        int col = n0 + wn + ni * 16 + l16;
        float v = acc[mi][ni][i];
        if (MODE == 0) {
          Cf[(size_t)row * Nn + col] = v;
        } else {
          if (col < NQc) {
            Cb[(size_t)row * NQc + col] = f2bf(v);             // q bf16
          } else if (col < NQc + NKVc) {
            Cf[(size_t)row * NKVc + (col - NQc)] = v;          // k f32
          } else {
            int nc = col - NQc - NKVc;
            Cf2[(size_t)row * NKVc + nc] = v;                  // v f32
            int b = row >> 11, s = row & (Sc - 1);
            Cb2[((size_t)(b * NKVc + nc)) * Sc + s] = f2bf(v); // v^T bf16
          }
        }
      }
}

// ------------------- fused RoPE (table-driven, vectorized) ------------------
// blocks [0,4096)    : q — thread = (m, h, e4): rotate 4 (e, e+64) pairs
// blocks [4096,5120) : k — thread = (m, kvh, e4): f32 in-place + bf16 out
// Table is 1 MB -> L2-resident; identical angle values as before (computed
// once in cvt_all), so numerics are unchanged.

__global__ void rope_all(unsigned short* qb, float* kf, unsigned short* kb,
                         const float2* __restrict__ tab) {
  int idx = blockIdx.x * 256 + threadIdx.x;
  if (blockIdx.x < 4096) {
    int e4 = idx & 15, h = (idx >> 4) & 15, m = idx >> 8;
    int s = m & (Sc - 1);
    size_t base = (size_t)m * NQc + h * Dhc + e4 * 4;
    ushort4 x1 = *(const ushort4*)(qb + base);
    ushort4 x2 = *(const ushort4*)(qb + base + 64);
    float4 ta = *(const float4*)(&tab[s * 64 + e4 * 4]);      // cs0 sn0 cs1 sn1
    float4 tbv = *(const float4*)(&tab[s * 64 + e4 * 4 + 2]); // cs2 sn2 cs3 sn3
    float a0 = bf2f(x1.x), a1 = bf2f(x1.y), a2 = bf2f(x1.z), a3 = bf2f(x1.w);
    float b0 = bf2f(x2.x), b1 = bf2f(x2.y), b2 = bf2f(x2.z), b3 = bf2f(x2.w);
    ushort4 o1, o2;
    o1.x = f2bf(a0 * ta.x - b0 * ta.y);  o2.x = f2bf(a0 * ta.y + b0 * ta.x);
    o1.y = f2bf(a1 * ta.z - b1 * ta.w);  o2.y = f2bf(a1 * ta.w + b1 * ta.z);
    o1.z = f2bf(a2 * tbv.x - b2 * tbv.y); o2.z = f2bf(a2 * tbv.y + b2 * tbv.x);
    o1.w = f2bf(a3 * tbv.z - b3 * tbv.w); o2.w = f2bf(a3 * tbv.w + b3 * tbv.z);
    *(ushort4*)(qb + base) = o1;
    *(ushort4*)(qb + base + 64) = o2;
  } else {
    int j = idx - 4096 * 256;
    int e4 = j & 15, kvh = (j >> 4) & 3, m = j >> 6;
    int s = m & (Sc - 1);
    size_t base = (size_t)m * NKVc + kvh * Dhc + e4 * 4;
    float4 x1 = *(const float4*)(kf + base);
    float4 x2 = *(const float4*)(kf + base + 64);
    float4 ta = *(const float4*)(&tab[s * 64 + e4 * 4]);
    float4 tbv = *(const float4*)(&tab[s * 64 + e4 * 4 + 2]);
    float4 o1, o2;
    o1.x = x1.x * ta.x - x2.x * ta.y;   o2.x = x1.x * ta.y + x2.x * ta.x;
    o1.y = x1.y * ta.z - x2.y * ta.w;   o2.y = x1.y * ta.w + x2.y * ta.z;
    o1.z = x1.z * tbv.x - x2.z * tbv.y; o2.z = x1.z * tbv.y + x2.z * tbv.x;
    o1.w = x1.w * tbv.z - x2.w * tbv.w; o2.w = x1.w * tbv.w + x2.w * tbv.z;
    *(float4*)(kf + base) = o1;
    *(float4*)(kf + base + 64) = o2;
    ushort4 k1, k2;
    k1.x = f2bf(o1.x); k1.y = f2bf(o1.y); k1.z = f2bf(o1.z); k1.w = f2bf(o1.w);
    k2.x = f2bf(o2.x); k2.y = f2bf(o2.y); k2.z = f2bf(o2.z); k2.w = f2bf(o2.w);
    *(ushort4*)(kb + base) = k1;
    *(ushort4*)(kb + base + 64) = k2;
  }
}

// ---------------------- flash attention (bf16 MFMA) ------------------------
// (unchanged; frozen-reference softmax, diagonal-first)

DEVI void issue_tile(const unsigned short* kb, const unsigned short* vbT,
                     int bb, int kvh, int kt, int t,
                     unsigned short* KsB, unsigned short* VtB) {
#pragma unroll
  for (int i = 0; i < 4; ++i) {
    int c = i * 256 + t;
    int row = c >> 4, chp = c & 15;
    int ch = chp ^ (row & 15);
    gload_lds16(kb + (size_t)(bb * Sc + kt * 64 + row) * NKVc + kvh * Dhc + ch * 8,
                KsB + c * 8);
  }
#pragma unroll
  for (int i = 0; i < 4; ++i) {
    int c = i * 256 + t;
    int row = c >> 3, chp = c & 7;       // Vt: 128 rows x 8 chunks
    int ch = chp ^ (row & 7);
    gload_lds16(vbT + ((size_t)(bb * KVHc + kvh) * Dhc + row) * Sc + kt * 64 + ch * 8,
                VtB + c * 8);
  }
}

DEVI void load_q(frag8 (&aQc)[4], const unsigned short* qb, int bb, int qt,
                 int h, int w, int quad, int l16) {
  const unsigned short* qrow =
      qb + (size_t)(bb * Sc + qt * 64 + w * 16 + l16) * NQc + h * Dhc;
#pragma unroll
  for (int kd = 0; kd < 4; ++kd)
    aQc[kd] = *(const frag8*)(qrow + (kd * 4 + quad) * 8);
}

DEVI void write_o(unsigned short* qb, facc4 (&oacc)[8], float (&lrow)[4],
                  int bb, int qt, int h, int w, int quad, int l16) {
  float rinv[4];
#pragma unroll
  for (int i = 0; i < 4; ++i) rinv[i] = 1.0f / rowred_sum(lrow[i]);
#pragma unroll
  for (int c8 = 0; c8 < 8; ++c8)
#pragma unroll
    for (int i = 0; i < 4; ++i) {
      int row = qt * 64 + w * 16 + quad * 4 + i;
      size_t o = ((size_t)(bb * Sc + row) * Hc + h) * Dhc + c8 * 16 + l16;
      qb[o] = f2bf(oacc[c8][i] * rinv[i]);
    }
}

__global__ __launch_bounds__(256, 2) void flash_attn(
    unsigned short* qb,                      // [M][H][Dh] bf16, in+out
    const unsigned short* __restrict__ kb,   // [M][KVH][Dh] bf16 (roped)
    const unsigned short* __restrict__ vbT,  // [B][KVH][Dh][S] bf16
    const int* __restrict__ spp) {
  __shared__ __align__(16) unsigned short Ks[2][64 * 128];
  __shared__ __align__(16) unsigned short Vt[2][128 * 64];
  __shared__ __align__(16) unsigned short Ps[4][16 * 64];

  int g = blockIdx.x & 7;
  int bb = g >> 2, kvh = g & 3;
  int inner = blockIdx.x >> 3;
  int pair = inner & 15, hh = inner >> 4;
  int h = kvh * 4 + hh;
  int qtA = pair, qtB = 31 - pair;

  int t = threadIdx.x, lane = t & 63, w = t >> 6;
  int quad = lane >> 4, l16 = lane & 15;
  int sp = spp[0];
  constexpr float LOG2E = 1.4426950408889634f;
  const float SC = 0.08838834764831845f * LOG2E;
  float slope2 = exp2f(-0.5f * (float)(h + 1)) * LOG2E;
  float s2x16 = slope2 * 16.0f;
  float s2x64 = slope2 * 64.0f;

  int tA = min((sp + qtA * 64 + 63) >> 6, 31) + 1;
  int tB = min((sp + qtB * 64 + 63) >> 6, 31) + 1;
  int total = tA + tB;

  frag8 aQc[4];
  load_q(aQc, qb, bb, qtA, h, w, quad, l16);

  facc4 oacc[8] = {};
  float mrow[4], lrow[4], bq[4], adn[4][4];
  int qposi[4];
  int qt = qtA;
#pragma unroll
  for (int i = 0; i < 4; ++i) {
    mrow[i] = -1e30f; lrow[i] = 0.f;
    qposi[i] = sp + qt * 64 + w * 16 + quad * 4 + i;
    bq[i] = slope2 * (float)qposi[i];
  }

  issue_tile(kb, vbT, bb, kvh, tA - 1, t, Ks[0], Vt[0]);

  for (int it = 0; it < total; ++it) {
    if (it == tA) {
      write_o(qb, oacc, lrow, bb, qtA, h, w, quad, l16);
      load_q(aQc, qb, bb, qtB, h, w, quad, l16);
      qt = qtB;
#pragma unroll
      for (int c8 = 0; c8 < 8; ++c8)
#pragma unroll
        for (int i = 0; i < 4; ++i) oacc[c8][i] = 0.f;
#pragma unroll
      for (int i = 0; i < 4; ++i) {
        mrow[i] = -1e30f; lrow[i] = 0.f;
        qposi[i] = sp + qt * 64 + w * 16 + quad * 4 + i;
        bq[i] = slope2 * (float)qposi[i];
      }
    }
    int kt = (it < tA) ? (tA - 1 - it) : (total - 1 - it);
    bool first = (it == 0) || (it == tA);

    if (it + 1 < total) {
      int nk = (it + 1 < tA) ? (tA - 2 - it) : (total - 2 - it);
      issue_tile(kb, vbT, bb, kvh, nk, t, Ks[(it + 1) & 1], Vt[(it + 1) & 1]);
      asm volatile("s_waitcnt vmcnt(8)" ::: "memory");
    } else {
      asm volatile("s_waitcnt vmcnt(0)" ::: "memory");
    }
    __builtin_amdgcn_s_barrier();
    asm volatile("" ::: "memory");

    const unsigned short* KsB = Ks[it & 1];
    const unsigned short* VtB = Vt[it & 1];

    facc4 sacc[4] = {};
#pragma unroll
    for (int kd = 0; kd < 4; ++kd) {
      int ch = kd * 4 + quad;
#pragma unroll
      for (int c4 = 0; c4 < 4; ++c4) {
        frag8 bK = *(const frag8*)&KsB[(c4 * 16 + l16) * 128 + (ch ^ l16) * 8];
        sacc[c4] = __builtin_amdgcn_mfma_f32_16x16x32_bf16(aQc[kd], bK, sacc[c4], 0, 0, 0);
      }
    }

    unsigned short* Pw = &Ps[w][0];
    int r0 = quad * 4;
    bool needmask = (kt * 64 + 63) > (sp + qt * 64);

    if (first || needmask) {
      float sv[4][4];
      float mt[4] = {-1e30f, -1e30f, -1e30f, -1e30f};
#pragma unroll
      for (int c4 = 0; c4 < 4; ++c4) {
        int kpos = kt * 64 + c4 * 16 + l16;
        float bk = slope2 * (float)kpos;
#pragma unroll
        for (int i = 0; i < 4; ++i) {
          float v = fmaf(sacc[c4][i], SC, bk - bq[i]);
          if (needmask) v = (kpos <= qposi[i]) ? v : -1e30f;
          sv[c4][i] = v;
          mt[i] = fmaxf(mt[i], v);
        }
      }
#pragma unroll
      for (int i = 0; i < 4; ++i) mt[i] = rowred_max(mt[i]);
#pragma unroll
      for (int i = 0; i < 4; ++i) {
        float mn = fmaxf(mrow[i], mt[i]);
        float alpha = exp2f(mrow[i] - mn);
        mrow[i] = mn;
        lrow[i] *= alpha;
#pragma unroll
        for (int c8 = 0; c8 < 8; ++c8) oacc[c8][i] *= alpha;
      }
#pragma unroll
      for (int c4 = 0; c4 < 4; ++c4) {
        float p0 = exp2f(sv[c4][0] - mrow[0]);
        float p1 = exp2f(sv[c4][1] - mrow[1]);
        float p2 = exp2f(sv[c4][2] - mrow[2]);
        float p3 = exp2f(sv[c4][3] - mrow[3]);
        lrow[0] += p0; lrow[1] += p1; lrow[2] += p2; lrow[3] += p3;
        unsigned u01, u23;
        asm("v_cvt_pk_bf16_f32 %0, %1, %2" : "=v"(u01) : "v"(p0), "v"(p1));
        asm("v_cvt_pk_bf16_f32 %0, %1, %2" : "=v"(u23) : "v"(p2), "v"(p3));
        int kk = c4 * 16 + l16;
        int col = kk & 7, chnk = kk >> 3;
        Pw[(r0 + 0) * 64 + ((chnk ^ ((r0 + 0) & 7)) * 8) + col] = (unsigned short)(u01 & 0xffffu);
        Pw[(r0 + 1) * 64 + ((chnk ^ ((r0 + 1) & 7)) * 8) + col] = (unsigned short)(u01 >> 16);
        Pw[(r0 + 2) * 64 + ((chnk ^ ((r0 + 2) & 7)) * 8) + col] = (unsigned short)(u23 & 0xffffu);
        Pw[(r0 + 3) * 64 + ((chnk ^ ((r0 + 3) & 7)) * 8) + col] = (unsigned short)(u23 >> 16);
      }
      float bkn0 = slope2 * (float)((kt - 1) * 64 + l16);
#pragma unroll
      for (int c4 = 0; c4 < 4; ++c4) {
        float bkc = bkn0 + (float)c4 * s2x16;
#pragma unroll
        for (int i = 0; i < 4; ++i) adn[c4][i] = bkc - bq[i] - mrow[i];
      }
    } else {
#pragma unroll
      for (int c4 = 0; c4 < 4; ++c4) {
        float p0 = exp2f(fmaf(sacc[c4][0], SC, adn[c4][0]));
        float p1 = exp2f(fmaf(sacc[c4][1], SC, adn[c4][1]));
        float p2 = exp2f(fmaf(sacc[c4][2], SC, adn[c4][2]));
        float p3 = exp2f(fmaf(sacc[c4][3], SC, adn[c4][3]));
        lrow[0] += p0; lrow[1] += p1; lrow[2] += p2; lrow[3] += p3;
        adn[c4][0] -= s2x64; adn[c4][1] -= s2x64;
        adn[c4][2] -= s2x64; adn[c4][3] -= s2x64;
        unsigned u01, u23;
        asm("v_cvt_pk_bf16_f32 %0, %1, %2" : "=v"(u01) : "v"(p0), "v"(p1));
        asm("v_cvt_pk_bf16_f32 %0, %1, %2" : "=v"(u23) : "v"(p2), "v"(p3));
        int kk = c4 * 16 + l16;
        int col = kk & 7, chnk = kk >> 3;
        Pw[(r0 + 0) * 64 + ((chnk ^ ((r0 + 0) & 7)) * 8) + col] = (unsigned short)(u01 & 0xffffu);
        Pw[(r0 + 1) * 64 + ((chnk ^ ((r0 + 1) & 7)) * 8) + col] = (unsigned short)(u01 >> 16);
        Pw[(r0 + 2) * 64 + ((chnk ^ ((r0 + 2) & 7)) * 8) + col] = (unsigned short)(u23 & 0xffffu);
        Pw[(r0 + 3) * 64 + ((chnk ^ ((r0 + 3) & 7)) * 8) + col] = (unsigned short)(u23 >> 16);
      }
    }

#pragma unroll
    for (int k2 = 0; k2 < 2; ++k2) {
      int ch = k2 * 4 + quad;
      frag8 aP = *(const frag8*)&Ps[w][l16 * 64 + (ch ^ (l16 & 7)) * 8];
#pragma unroll
      for (int c8 = 0; c8 < 8; ++c8) {
        frag8 bV = *(const frag8*)&VtB[(c8 * 16 + l16) * 64 + (ch ^ (l16 & 7)) * 8];
        oacc[c8] = __builtin_amdgcn_mfma_f32_16x16x32_bf16(aP, bV, oacc[c8], 0, 0, 0);
      }
    }

    if (!first) {
      int ovf = (lrow[0] > 16777216.f) || (lrow[1] > 16777216.f) ||
                (lrow[2] > 16777216.f) || (lrow[3] > 16777216.f);
      if (__any(ovf)) {
        const float DS = 0x1p-32f;
#pragma unroll
        for (int i = 0; i < 4; ++i) { lrow[i] *= DS; mrow[i] += 32.f; }
#pragma unroll
        for (int c4 = 0; c4 < 4; ++c4)
#pragma unroll
          for (int i = 0; i < 4; ++i) adn[c4][i] -= 32.f;
#pragma unroll
        for (int c8 = 0; c8 < 8; ++c8)
#pragma unroll
          for (int i = 0; i < 4; ++i) oacc[c8][i] *= DS;
      }
    }

    asm volatile("" ::: "memory");
    __builtin_amdgcn_s_barrier();
  }

  write_o(qb, oacc, lrow, bb, qtB, h, w, quad, l16);
}

// ------------------------------- launcher ----------------------------------

extern "C" void kernel_launch(void* const* d_in, const int* in_sizes, int n_in,
                              void* d_out, int out_size, void* d_ws, size_t ws_size,
                              hipStream_t stream) {
  const float* residual = (const float*)d_in[0];
  const float* W_Q = (const float*)d_in[1];
  const float* W_K = (const float*)d_in[2];
  const float* W_V = (const float*)d_in[3];
  const float* W_O = (const float*)d_in[4];
  const int* start_pos = (const int*)d_in[5];

  float* out = (float*)d_out;                        // [2][2048][2048]
  float* kf = out + (size_t)Bc * Sc * Dc;            // [4096][512] fp32 k cache
  float* vf = kf + (size_t)Mc * NKVc;                // [4096][512] fp32 v cache

  char* w = (char*)d_ws;
  auto alloc = [&](size_t bytes) {
    char* p = w; w += (bytes + 255) & ~(size_t)255; return p;
  };
  unsigned short* rb   = (unsigned short*)alloc((size_t)Mc * Dc * 2);
  unsigned short* wqkv = (unsigned short*)alloc((size_t)(NQc + 2 * NKVc) * Dc * 2); // [Q;K;V] rows
  unsigned short* wob  = (unsigned short*)alloc((size_t)Dc * NQc * 2);
  unsigned short* qb   = (unsigned short*)alloc((size_t)Mc * NQc * 2);
  unsigned short* kb   = (unsigned short*)alloc((size_t)Mc * NKVc * 2);
  unsigned short* vbT  = (unsigned short*)alloc((size_t)Mc * NKVc * 2);
  float2* tab          = (float2*)alloc((size_t)Sc * 64 * sizeof(float2));  // 1 MB
  (void)ws_size; (void)in_sizes; (void)n_in; (void)out_size;

  // one fused converter launch (+ RoPE table); W_K/W_V land after W_Q rows
  cvt_all<<<15872, 256, 0, stream>>>(residual, W_Q, W_K, W_V, W_O,
                                     rb, wqkv, wqkv + (size_t)NQc * Dc, wob,
                                     tab, start_pos);

  // fused QKV projection: N = 2048(Q) + 512(K) + 512(V) = 3072
  gemm2b<1><<<dim3(32, 24), 256, 0, stream>>>(rb, wqkv, kf, vf, qb, vbT,
                                              NQc + 2 * NKVc, Dc);

  // fused RoPE (q + k), table-driven
  rope_all<<<5120, 256, 0, stream>>>(qb, kf, kb, tab);

  flash_attn<<<512, 256, 0, stream>>>(qb, kb, vbT, start_pos);

  // output projection: attn (in qb) x W_O^T -> d_out
  gemm2b<0><<<dim3(32, 16), 256, 0, stream>>>(qb, wob, out, nullptr, nullptr,
                                              nullptr, Dc, Dc);
}

// Round 9
// 308.213 us; speedup vs baseline: 1.8354x; 1.0659x over previous
//
#include <hip/hip_runtime.h>

// ---------------------------------------------------------------------------
// AttentionWithEinops: B=2,S=2048,D=2048,H=16,KVH=4,Dh=128, start_pos input.
// bf16 MFMA everywhere (fp32 accumulate), fp32 outputs.
// d_out = [output 2*2048*2048][k_cache 2*2048*4*128][v_cache 2*2048*4*128]
// ---------------------------------------------------------------------------

typedef __attribute__((ext_vector_type(8))) short frag8;   // 8 x bf16 (4 VGPR)
typedef __attribute__((ext_vector_type(4))) float facc4;   // 4 x f32 acc

#define DEVI __device__ __forceinline__

constexpr int Bc  = 2;
constexpr int Sc  = 2048;
constexpr int Dc  = 2048;
constexpr int Hc  = 16;
constexpr int KVHc = 4;
constexpr int Dhc = 128;
constexpr int Mc  = Bc * Sc;       // 4096
constexpr int NQc = Hc * Dhc;      // 2048
constexpr int NKVc = KVHc * Dhc;   // 512

DEVI unsigned short f2bf(float f) {
  union { float f; unsigned u; } v; v.f = f;
  return (unsigned short)((v.u + 0x7fffu + ((v.u >> 16) & 1u)) >> 16);
}
DEVI float bf2f(unsigned short h) {
  union { unsigned u; float f; } v; v.u = ((unsigned)h) << 16;
  return v.f;
}

DEVI void gload_lds16(const void* g, void* l) {
  __builtin_amdgcn_global_load_lds(
      (const __attribute__((address_space(1))) unsigned int*)g,
      (__attribute__((address_space(3))) unsigned int*)l, 16, 0, 0);
}

// DPP rotate-combine reduce over the 16-lane row (no LDS traffic).
DEVI float rowred_max(float x) {
  union { float f; int i; } a, b;
  a.f = x;
  b.i = __builtin_amdgcn_update_dpp(a.i, a.i, 0x128, 0xF, 0xF, false); a.f = fmaxf(a.f, b.f);
  b.i = __builtin_amdgcn_update_dpp(a.i, a.i, 0x124, 0xF, 0xF, false); a.f = fmaxf(a.f, b.f);
  b.i = __builtin_amdgcn_update_dpp(a.i, a.i, 0x122, 0xF, 0xF, false); a.f = fmaxf(a.f, b.f);
  b.i = __builtin_amdgcn_update_dpp(a.i, a.i, 0x121, 0xF, 0xF, false); a.f = fmaxf(a.f, b.f);
  return a.f;
}
DEVI float rowred_sum(float x) {
  union { float f; int i; } a, b;
  a.f = x;
  b.i = __builtin_amdgcn_update_dpp(a.i, a.i, 0x128, 0xF, 0xF, false); a.f += b.f;
  b.i = __builtin_amdgcn_update_dpp(a.i, a.i, 0x124, 0xF, 0xF, false); a.f += b.f;
  b.i = __builtin_amdgcn_update_dpp(a.i, a.i, 0x122, 0xF, 0xF, false); a.f += b.f;
  b.i = __builtin_amdgcn_update_dpp(a.i, a.i, 0x121, 0xF, 0xF, false); a.f += b.f;
  return a.f;
}

// ------------------- fused converters + RoPE table (one launch) ------------
// blocks [0,8192)        : residual f32->bf16
// blocks [8192,12288)    : W_Q
// blocks [12288,13312)   : W_K
// blocks [13312,14336)   : W_V
// blocks [14336,15360)   : W_O transpose
// blocks [15360,15872)   : RoPE cos/sin table: tab[s*64+e] = {cos,sin} of
//                          (sp+s) * base^(-e/64); 131K sincos once here vs
//                          6.3M scalar sincosf in a standalone rope kernel.

__global__ void cvt_all(const float* __restrict__ residual,
                        const float* __restrict__ WQ,
                        const float* __restrict__ WK,
                        const float* __restrict__ WV,
                        const float* __restrict__ WO,
                        unsigned short* __restrict__ rb,
                        unsigned short* __restrict__ wqb,
                        unsigned short* __restrict__ wkvb,
                        unsigned short* __restrict__ wob,
                        float2* __restrict__ tab,
                        const int* __restrict__ sp) {
  __shared__ float tile[64][65];
  int bid = blockIdx.x;
  int t = threadIdx.x;
  if (bid < 14336) {
    const float* src; unsigned short* dst; int off;
    if (bid < 8192)       { src = residual; dst = rb;  off = bid; }
    else if (bid < 12288) { src = WQ; dst = wqb; off = bid - 8192; }
    else if (bid < 13312) { src = WK; dst = wkvb; off = bid - 12288; }
    else                  { src = WV; dst = wkvb + (size_t)NKVc * Dc; off = bid - 13312; }
    int i = (off * 256 + t) * 4;
    float4 v = *(const float4*)(src + i);
    ushort4 o;
    o.x = f2bf(v.x); o.y = f2bf(v.y); o.z = f2bf(v.z); o.w = f2bf(v.w);
    *(ushort4*)(dst + i) = o;
  } else if (bid < 15360) {
    int tb = bid - 14336;
    int r0 = (tb >> 5) * 64;   // he base
    int c0 = (tb & 31) * 64;   // d base
#pragma unroll
    for (int i = 0; i < 16; ++i) {
      int idx = i * 256 + t; int r = idx >> 6, c = idx & 63;
      tile[r][c] = WO[(size_t)(r0 + r) * Dc + c0 + c];
    }
    __syncthreads();
#pragma unroll
    for (int i = 0; i < 16; ++i) {
      int idx = i * 256 + t; int r = idx >> 6, c = idx & 63;
      wob[(size_t)(c0 + r) * NQc + r0 + c] = f2bf(tile[c][r]);
    }
  } else {
    int idx = (bid - 15360) * 256 + t;   // 131072 (s,e) entries
    int s = idx >> 6, e = idx & 63;
    float ang = (float)(sp[0] + s) * exp2f(-(float)e * 0.20762050593046835f);
    float sn, cs; sincosf(ang, &sn, &cs);
    tab[idx] = make_float2(cs, sn);
  }
}

// ----- double-buffered NT GEMM, counted vmcnt (depth-2 pipeline, T4) -------
// C[M,N] = A[M,K](bf16) * B[N,K](bf16)^T.
// BM=128, BN=128, BK=64; 256 thr = 4 waves (2M x 2N); per-wave 64x64 (acc 4x4).
// LDS 64 KB double-buffered. EXACT R6 structure (82 us, best of 4 measured
// variants). Per K-tile:
//   ds_read frags(buf p) x16 ; lgkmcnt(0) ; s_barrier   (buf p reads done)
//   stage(t+2) -> buf p  [STAGE-EARLY: issued BEFORE the MFMA cluster so
//                         t+1's loads are in flight across a FULL iteration
//                         -- R8's stage-late reorder cost 82->96 us]
//   MFMA x32 (setprio 1)
//   s_waitcnt vmcnt(8)  [t+1 landed; t+2's 8 stay in flight] ; s_barrier
// Never vmcnt(0) mid-loop. NO min-occupancy launch_bounds (R7: VGPR 48 ->
// accumulator scratch-spill, 400 MB writes). NO BK=32 (4-way LDS conflicts).
// Swizzle (0 conflicts, R4-R6): [row][8 chunks of 16B], chunk ^= (row&7);
// linear LDS dest + inverse-permuted global source + same XOR on ds_read.
// XCD remap (T1): each XCD owns a contiguous band of n-panels.
// MODE 0: o-proj (f32 out).  MODE 1: fused QKV (q bf16 / k f32 / v f32+bf16^T).

DEVI void stage_tile(const unsigned short* A, const unsigned short* B,
                     unsigned short* Al, unsigned short* Bl,
                     int m0, int n0, int kt, int t, int Kk) {
#pragma unroll
  for (int i = 0; i < 4; ++i) {
    int c = i * 256 + t;                 // 1024 chunks: 128 rows x 8 of 16B
    int row = c >> 3, ch = c & 7;
    int g = ch ^ (row & 7);              // inverse-permuted global chunk
    gload_lds16(A + (size_t)(m0 + row) * Kk + kt * 64 + g * 8, Al + c * 8);
  }
#pragma unroll
  for (int i = 0; i < 4; ++i) {
    int c = i * 256 + t;
    int row = c >> 3, ch = c & 7;
    int g = ch ^ (row & 7);
    gload_lds16(B + (size_t)(n0 + row) * Kk + kt * 64 + g * 8, Bl + c * 8);
  }
}

template <int MODE>
__global__ __launch_bounds__(256, 2) void gemm2b(
    const unsigned short* __restrict__ Amat,
    const unsigned short* __restrict__ Bmat,
    float* __restrict__ Cf, float* __restrict__ Cf2,
    unsigned short* __restrict__ Cb, unsigned short* __restrict__ Cb2,
    int Nn, int Kk) {
  __shared__ __align__(16) unsigned short As[2][128 * 64];
  __shared__ __align__(16) unsigned short Bs[2][128 * 64];

  int t = threadIdx.x;
  int lane = t & 63, w = t >> 6;
  int quad = lane >> 4, l16 = lane & 15;
  int l7 = l16 & 7;
  int wm = (w >> 1) * 64, wn = (w & 1) * 64;

  // XCD-aware remap: consecutive dispatch ids round-robin XCDs; give each
  // XCD a contiguous band of n-panels so B-panels are L2-resident per XCD.
  int lin = blockIdx.x + gridDim.x * blockIdx.y;
  int xcd = lin & 7, gg = lin >> 3;
  int ypx = gridDim.y >> 3;             // n-panels per XCD (3 QKV / 2 o-proj)
  int ny = xcd * ypx + (gg % ypx);
  int nx = gg / ypx;
  int m0 = nx * 128, n0 = ny * 128;
  const int NT = Kk >> 6;

  // swizzled ds_read offsets (ushort idx): row*64 + ((ks*4+quad)^(row&7))*8;
  // row&7 == l16&7 (wm, wn, mi*16, ni*16 are multiples of 16).
  auto aoff = [&](int mi, int ks) {
    return (wm + mi * 16 + l16) * 64 + (((ks * 4 + quad) ^ l7) * 8);
  };
  auto boff = [&](int ni, int ks) {
    return (wn + ni * 16 + l16) * 64 + (((ks * 4 + quad) ^ l7) * 8);
  };

  // prologue: stage tiles 0 and 1; wait tile 0 landed (tile 1's 8 in flight)
  stage_tile(Amat, Bmat, As[0], Bs[0], m0, n0, 0, t, Kk);
  if (NT > 1) stage_tile(Amat, Bmat, As[1], Bs[1], m0, n0, 1, t, Kk);
  if (NT > 1) asm volatile("s_waitcnt vmcnt(8)" ::: "memory");
  else        asm volatile("s_waitcnt vmcnt(0)" ::: "memory");
  __builtin_amdgcn_s_barrier();
  asm volatile("" ::: "memory");

  facc4 acc[4][4] = {};

  for (int kt = 0; kt < NT; ++kt) {
    const int p = kt & 1;
    const unsigned short* Ab = As[p];
    const unsigned short* Bb = Bs[p];
    frag8 aFr[4][2], bFr[4][2];
#pragma unroll
    for (int ks = 0; ks < 2; ++ks) {
#pragma unroll
      for (int mi = 0; mi < 4; ++mi) aFr[mi][ks] = *(const frag8*)&Ab[aoff(mi, ks)];
#pragma unroll
      for (int ni = 0; ni < 4; ++ni) bFr[ni][ks] = *(const frag8*)&Bb[boff(ni, ks)];
    }
    // reads of buf[p] complete before any wave overwrites it
    asm volatile("s_waitcnt lgkmcnt(0)" ::: "memory");
    __builtin_amdgcn_s_barrier();
    asm volatile("" ::: "memory");

    // stage tile kt+2 into buf[p] (just freed); 8 loads/thread in flight
    if (kt + 2 < NT)
      stage_tile(Amat, Bmat, As[p], Bs[p], m0, n0, kt + 2, t, Kk);

    __builtin_amdgcn_s_setprio(1);
#pragma unroll
    for (int ks = 0; ks < 2; ++ks)
#pragma unroll
      for (int mi = 0; mi < 4; ++mi)
#pragma unroll
        for (int ni = 0; ni < 4; ++ni)
          acc[mi][ni] = __builtin_amdgcn_mfma_f32_16x16x32_bf16(
              aFr[mi][ks], bFr[ni][ks], acc[mi][ni], 0, 0, 0);
    __builtin_amdgcn_s_setprio(0);

    // tile kt+1 landed (kt+2's 8 loads stay in flight); publish via barrier
    if (kt + 2 < NT) asm volatile("s_waitcnt vmcnt(8)" ::: "memory");
    else             asm volatile("s_waitcnt vmcnt(0)" ::: "memory");
    __builtin_amdgcn_s_barrier();
    asm volatile("" ::: "memory");
  }

  // ---- epilogue ----
#pragma unroll
  for (int mi = 0; mi < 4; ++mi)
#pragma unroll
    for (int ni = 0; ni < 4; ++ni)
#pragma unroll
      for (int i = 0; i < 4; ++i) {
        int row = m0 + wm + mi * 16 + quad * 4 + i;
        int col = n0 + wn + ni * 16 + l16;
        float v = acc[mi][ni][i];
        if (MODE == 0) {
          Cf[(size_t)row * Nn + col] = v;
        } else {
          if (col < NQc) {
            Cb[(size_t)row * NQc + col] = f2bf(v);             // q bf16
          } else if (col < NQc + NKVc) {
            Cf[(size_t)row * NKVc + (col - NQc)] = v;          // k f32
          } else {
            int nc = col - NQc - NKVc;
            Cf2[(size_t)row * NKVc + nc] = v;                  // v f32
            int b = row >> 11, s = row & (Sc - 1);
            Cb2[((size_t)(b * NKVc + nc)) * Sc + s] = f2bf(v); // v^T bf16
          }
        }
      }
}

// ------------------- fused RoPE (table-driven, vectorized) ------------------
// blocks [0,4096)    : q — thread = (m, h, e4): rotate 4 (e, e+64) pairs
// blocks [4096,5120) : k — thread = (m, kvh, e4): f32 in-place + bf16 out
// Table is 1 MB -> L2-resident; identical angle values (computed once in
// cvt_all), so numerics are unchanged (verified R8: absmax identical).

__global__ void rope_all(unsigned short* qb, float* kf, unsigned short* kb,
                         const float2* __restrict__ tab) {
  int idx = blockIdx.x * 256 + threadIdx.x;
  if (blockIdx.x < 4096) {
    int e4 = idx & 15, h = (idx >> 4) & 15, m = idx >> 8;
    int s = m & (Sc - 1);
    size_t base = (size_t)m * NQc + h * Dhc + e4 * 4;
    ushort4 x1 = *(const ushort4*)(qb + base);
    ushort4 x2 = *(const ushort4*)(qb + base + 64);
    float4 ta = *(const float4*)(&tab[s * 64 + e4 * 4]);      // cs0 sn0 cs1 sn1
    float4 tbv = *(const float4*)(&tab[s * 64 + e4 * 4 + 2]); // cs2 sn2 cs3 sn3
    float a0 = bf2f(x1.x), a1 = bf2f(x1.y), a2 = bf2f(x1.z), a3 = bf2f(x1.w);
    float b0 = bf2f(x2.x), b1 = bf2f(x2.y), b2 = bf2f(x2.z), b3 = bf2f(x2.w);
    ushort4 o1, o2;
    o1.x = f2bf(a0 * ta.x - b0 * ta.y);  o2.x = f2bf(a0 * ta.y + b0 * ta.x);
    o1.y = f2bf(a1 * ta.z - b1 * ta.w);  o2.y = f2bf(a1 * ta.w + b1 * ta.z);
    o1.z = f2bf(a2 * tbv.x - b2 * tbv.y); o2.z = f2bf(a2 * tbv.y + b2 * tbv.x);
    o1.w = f2bf(a3 * tbv.z - b3 * tbv.w); o2.w = f2bf(a3 * tbv.w + b3 * tbv.z);
    *(ushort4*)(qb + base) = o1;
    *(ushort4*)(qb + base + 64) = o2;
  } else {
    int j = idx - 4096 * 256;
    int e4 = j & 15, kvh = (j >> 4) & 3, m = j >> 6;
    int s = m & (Sc - 1);
    size_t base = (size_t)m * NKVc + kvh * Dhc + e4 * 4;
    float4 x1 = *(const float4*)(kf + base);
    float4 x2 = *(const float4*)(kf + base + 64);
    float4 ta = *(const float4*)(&tab[s * 64 + e4 * 4]);
    float4 tbv = *(const float4*)(&tab[s * 64 + e4 * 4 + 2]);
    float4 o1, o2;
    o1.x = x1.x * ta.x - x2.x * ta.y;   o2.x = x1.x * ta.y + x2.x * ta.x;
    o1.y = x1.y * ta.z - x2.y * ta.w;   o2.y = x1.y * ta.w + x2.y * ta.z;
    o1.z = x1.z * tbv.x - x2.z * tbv.y; o2.z = x1.z * tbv.y + x2.z * tbv.x;
    o1.w = x1.w * tbv.z - x2.w * tbv.w; o2.w = x1.w * tbv.w + x2.w * tbv.z;
    *(float4*)(kf + base) = o1;
    *(float4*)(kf + base + 64) = o2;
    ushort4 k1, k2;
    k1.x = f2bf(o1.x); k1.y = f2bf(o1.y); k1.z = f2bf(o1.z); k1.w = f2bf(o1.w);
    k2.x = f2bf(o2.x); k2.y = f2bf(o2.y); k2.z = f2bf(o2.z); k2.w = f2bf(o2.w);
    *(ushort4*)(kb + base) = k1;
    *(ushort4*)(kb + base + 64) = k2;
  }
}

// ---------------------- flash attention (bf16 MFMA) ------------------------
// (unchanged; frozen-reference softmax, diagonal-first)

DEVI void issue_tile(const unsigned short* kb, const unsigned short* vbT,
                     int bb, int kvh, int kt, int t,
                     unsigned short* KsB, unsigned short* VtB) {
#pragma unroll
  for (int i = 0; i < 4; ++i) {
    int c = i * 256 + t;
    int row = c >> 4, chp = c & 15;
    int ch = chp ^ (row & 15);
    gload_lds16(kb + (size_t)(bb * Sc + kt * 64 + row) * NKVc + kvh * Dhc + ch * 8,
                KsB + c * 8);
  }
#pragma unroll
  for (int i = 0; i < 4; ++i) {
    int c = i * 256 + t;
    int row = c >> 3, chp = c & 7;       // Vt: 128 rows x 8 chunks
    int ch = chp ^ (row & 7);
    gload_lds16(vbT + ((size_t)(bb * KVHc + kvh) * Dhc + row) * Sc + kt * 64 + ch * 8,
                VtB + c * 8);
  }
}

DEVI void load_q(frag8 (&aQc)[4], const unsigned short* qb, int bb, int qt,
                 int h, int w, int quad, int l16) {
  const unsigned short* qrow =
      qb + (size_t)(bb * Sc + qt * 64 + w * 16 + l16) * NQc + h * Dhc;
#pragma unroll
  for (int kd = 0; kd < 4; ++kd)
    aQc[kd] = *(const frag8*)(qrow + (kd * 4 + quad) * 8);
}

DEVI void write_o(unsigned short* qb, facc4 (&oacc)[8], float (&lrow)[4],
                  int bb, int qt, int h, int w, int quad, int l16) {
  float rinv[4];
#pragma unroll
  for (int i = 0; i < 4; ++i) rinv[i] = 1.0f / rowred_sum(lrow[i]);
#pragma unroll
  for (int c8 = 0; c8 < 8; ++c8)
#pragma unroll
    for (int i = 0; i < 4; ++i) {
      int row = qt * 64 + w * 16 + quad * 4 + i;
      size_t o = ((size_t)(bb * Sc + row) * Hc + h) * Dhc + c8 * 16 + l16;
      qb[o] = f2bf(oacc[c8][i] * rinv[i]);
    }
}

__global__ __launch_bounds__(256, 2) void flash_attn(
    unsigned short* qb,                      // [M][H][Dh] bf16, in+out
    const unsigned short* __restrict__ kb,   // [M][KVH][Dh] bf16 (roped)
    const unsigned short* __restrict__ vbT,  // [B][KVH][Dh][S] bf16
    const int* __restrict__ spp) {
  __shared__ __align__(16) unsigned short Ks[2][64 * 128];
  __shared__ __align__(16) unsigned short Vt[2][128 * 64];
  __shared__ __align__(16) unsigned short Ps[4][16 * 64];

  int g = blockIdx.x & 7;
  int bb = g >> 2, kvh = g & 3;
  int inner = blockIdx.x >> 3;
  int pair = inner & 15, hh = inner >> 4;
  int h = kvh * 4 + hh;
  int qtA = pair, qtB = 31 - pair;

  int t = threadIdx.x, lane = t & 63, w = t >> 6;
  int quad = lane >> 4, l16 = lane & 15;
  int sp = spp[0];
  constexpr float LOG2E = 1.4426950408889634f;
  const float SC = 0.08838834764831845f * LOG2E;
  float slope2 = exp2f(-0.5f * (float)(h + 1)) * LOG2E;
  float s2x16 = slope2 * 16.0f;
  float s2x64 = slope2 * 64.0f;

  int tA = min((sp + qtA * 64 + 63) >> 6, 31) + 1;
  int tB = min((sp + qtB * 64 + 63) >> 6, 31) + 1;
  int total = tA + tB;

  frag8 aQc[4];
  load_q(aQc, qb, bb, qtA, h, w, quad, l16);

  facc4 oacc[8] = {};
  float mrow[4], lrow[4], bq[4], adn[4][4];
  int qposi[4];
  int qt = qtA;
#pragma unroll
  for (int i = 0; i < 4; ++i) {
    mrow[i] = -1e30f; lrow[i] = 0.f;
    qposi[i] = sp + qt * 64 + w * 16 + quad * 4 + i;
    bq[i] = slope2 * (float)qposi[i];
  }

  issue_tile(kb, vbT, bb, kvh, tA - 1, t, Ks[0], Vt[0]);

  for (int it = 0; it < total; ++it) {
    if (it == tA) {
      write_o(qb, oacc, lrow, bb, qtA, h, w, quad, l16);
      load_q(aQc, qb, bb, qtB, h, w, quad, l16);
      qt = qtB;
#pragma unroll
      for (int c8 = 0; c8 < 8; ++c8)
#pragma unroll
        for (int i = 0; i < 4; ++i) oacc[c8][i] = 0.f;
#pragma unroll
      for (int i = 0; i < 4; ++i) {
        mrow[i] = -1e30f; lrow[i] = 0.f;
        qposi[i] = sp + qt * 64 + w * 16 + quad * 4 + i;
        bq[i] = slope2 * (float)qposi[i];
      }
    }
    int kt = (it < tA) ? (tA - 1 - it) : (total - 1 - it);
    bool first = (it == 0) || (it == tA);

    if (it + 1 < total) {
      int nk = (it + 1 < tA) ? (tA - 2 - it) : (total - 2 - it);
      issue_tile(kb, vbT, bb, kvh, nk, t, Ks[(it + 1) & 1], Vt[(it + 1) & 1]);
      asm volatile("s_waitcnt vmcnt(8)" ::: "memory");
    } else {
      asm volatile("s_waitcnt vmcnt(0)" ::: "memory");
    }
    __builtin_amdgcn_s_barrier();
    asm volatile("" ::: "memory");

    const unsigned short* KsB = Ks[it & 1];
    const unsigned short* VtB = Vt[it & 1];

    facc4 sacc[4] = {};
#pragma unroll
    for (int kd = 0; kd < 4; ++kd) {
      int ch = kd * 4 + quad;
#pragma unroll
      for (int c4 = 0; c4 < 4; ++c4) {
        frag8 bK = *(const frag8*)&KsB[(c4 * 16 + l16) * 128 + (ch ^ l16) * 8];
        sacc[c4] = __builtin_amdgcn_mfma_f32_16x16x32_bf16(aQc[kd], bK, sacc[c4], 0, 0, 0);
      }
    }

    unsigned short* Pw = &Ps[w][0];
    int r0 = quad * 4;
    bool needmask = (kt * 64 + 63) > (sp + qt * 64);

    if (first || needmask) {
      float sv[4][4];
      float mt[4] = {-1e30f, -1e30f, -1e30f, -1e30f};
#pragma unroll
      for (int c4 = 0; c4 < 4; ++c4) {
        int kpos = kt * 64 + c4 * 16 + l16;
        float bk = slope2 * (float)kpos;
#pragma unroll
        for (int i = 0; i < 4; ++i) {
          float v = fmaf(sacc[c4][i], SC, bk - bq[i]);
          if (needmask) v = (kpos <= qposi[i]) ? v : -1e30f;
          sv[c4][i] = v;
          mt[i] = fmaxf(mt[i], v);
        }
      }
#pragma unroll
      for (int i = 0; i < 4; ++i) mt[i] = rowred_max(mt[i]);
#pragma unroll
      for (int i = 0; i < 4; ++i) {
        float mn = fmaxf(mrow[i], mt[i]);
        float alpha = exp2f(mrow[i] - mn);
        mrow[i] = mn;
        lrow[i] *= alpha;
#pragma unroll
        for (int c8 = 0; c8 < 8; ++c8) oacc[c8][i] *= alpha;
      }
#pragma unroll
      for (int c4 = 0; c4 < 4; ++c4) {
        float p0 = exp2f(sv[c4][0] - mrow[0]);
        float p1 = exp2f(sv[c4][1] - mrow[1]);
        float p2 = exp2f(sv[c4][2] - mrow[2]);
        float p3 = exp2f(sv[c4][3] - mrow[3]);
        lrow[0] += p0; lrow[1] += p1; lrow[2] += p2; lrow[3] += p3;
        unsigned u01, u23;
        asm("v_cvt_pk_bf16_f32 %0, %1, %2" : "=v"(u01) : "v"(p0), "v"(p1));
        asm("v_cvt_pk_bf16_f32 %0, %1, %2" : "=v"(u23) : "v"(p2), "v"(p3));
        int kk = c4 * 16 + l16;
        int col = kk & 7, chnk = kk >> 3;
        Pw[(r0 + 0) * 64 + ((chnk ^ ((r0 + 0) & 7)) * 8) + col] = (unsigned short)(u01 & 0xffffu);
        Pw[(r0 + 1) * 64 + ((chnk ^ ((r0 + 1) & 7)) * 8) + col] = (unsigned short)(u01 >> 16);
        Pw[(r0 + 2) * 64 + ((chnk ^ ((r0 + 2) & 7)) * 8) + col] = (unsigned short)(u23 & 0xffffu);
        Pw[(r0 + 3) * 64 + ((chnk ^ ((r0 + 3) & 7)) * 8) + col] = (unsigned short)(u23 >> 16);
      }
      float bkn0 = slope2 * (float)((kt - 1) * 64 + l16);
#pragma unroll
      for (int c4 = 0; c4 < 4; ++c4) {
        float bkc = bkn0 + (float)c4 * s2x16;
#pragma unroll
        for (int i = 0; i < 4; ++i) adn[c4][i] = bkc - bq[i] - mrow[i];
      }
    } else {
#pragma unroll
      for (int c4 = 0; c4 < 4; ++c4) {
        float p0 = exp2f(fmaf(sacc[c4][0], SC, adn[c4][0]));
        float p1 = exp2f(fmaf(sacc[c4][1], SC, adn[c4][1]));
        float p2 = exp2f(fmaf(sacc[c4][2], SC, adn[c4][2]));
        float p3 = exp2f(fmaf(sacc[c4][3], SC, adn[c4][3]));
        lrow[0] += p0; lrow[1] += p1; lrow[2] += p2; lrow[3] += p3;
        adn[c4][0] -= s2x64; adn[c4][1] -= s2x64;
        adn[c4][2] -= s2x64; adn[c4][3] -= s2x64;
        unsigned u01, u23;
        asm("v_cvt_pk_bf16_f32 %0, %1, %2" : "=v"(u01) : "v"(p0), "v"(p1));
        asm("v_cvt_pk_bf16_f32 %0, %1, %2" : "=v"(u23) : "v"(p2), "v"(p3));
        int kk = c4 * 16 + l16;
        int col = kk & 7, chnk = kk >> 3;
        Pw[(r0 + 0) * 64 + ((chnk ^ ((r0 + 0) & 7)) * 8) + col] = (unsigned short)(u01 & 0xffffu);
        Pw[(r0 + 1) * 64 + ((chnk ^ ((r0 + 1) & 7)) * 8) + col] = (unsigned short)(u01 >> 16);
        Pw[(r0 + 2) * 64 + ((chnk ^ ((r0 + 2) & 7)) * 8) + col] = (unsigned short)(u23 & 0xffffu);
        Pw[(r0 + 3) * 64 + ((chnk ^ ((r0 + 3) & 7)) * 8) + col] = (unsigned short)(u23 >> 16);
      }
    }

#pragma unroll
    for (int k2 = 0; k2 < 2; ++k2) {
      int ch = k2 * 4 + quad;
      frag8 aP = *(const frag8*)&Ps[w][l16 * 64 + (ch ^ (l16 & 7)) * 8];
#pragma unroll
      for (int c8 = 0; c8 < 8; ++c8) {
        frag8 bV = *(const frag8*)&VtB[(c8 * 16 + l16) * 64 + (ch ^ (l16 & 7)) * 8];
        oacc[c8] = __builtin_amdgcn_mfma_f32_16x16x32_bf16(aP, bV, oacc[c8], 0, 0, 0);
      }
    }

    if (!first) {
      int ovf = (lrow[0] > 16777216.f) || (lrow[1] > 16777216.f) ||
                (lrow[2] > 16777216.f) || (lrow[3] > 16777216.f);
      if (__any(ovf)) {
        const float DS = 0x1p-32f;
#pragma unroll
        for (int i = 0; i < 4; ++i) { lrow[i] *= DS; mrow[i] += 32.f; }
#pragma unroll
        for (int c4 = 0; c4 < 4; ++c4)
#pragma unroll
          for (int i = 0; i < 4; ++i) adn[c4][i] -= 32.f;
#pragma unroll
        for (int c8 = 0; c8 < 8; ++c8)
#pragma unroll
          for (int i = 0; i < 4; ++i) oacc[c8][i] *= DS;
      }
    }

    asm volatile("" ::: "memory");
    __builtin_amdgcn_s_barrier();
  }

  write_o(qb, oacc, lrow, bb, qtB, h, w, quad, l16);
}

// ------------------------------- launcher ----------------------------------

extern "C" void kernel_launch(void* const* d_in, const int* in_sizes, int n_in,
                              void* d_out, int out_size, void* d_ws, size_t ws_size,
                              hipStream_t stream) {
  const float* residual = (const float*)d_in[0];
  const float* W_Q = (const float*)d_in[1];
  const float* W_K = (const float*)d_in[2];
  const float* W_V = (const float*)d_in[3];
  const float* W_O = (const float*)d_in[4];
  const int* start_pos = (const int*)d_in[5];

  float* out = (float*)d_out;                        // [2][2048][2048]
  float* kf = out + (size_t)Bc * Sc * Dc;            // [4096][512] fp32 k cache
  float* vf = kf + (size_t)Mc * NKVc;                // [4096][512] fp32 v cache

  char* w = (char*)d_ws;
  auto alloc = [&](size_t bytes) {
    char* p = w; w += (bytes + 255) & ~(size_t)255; return p;
  };
  unsigned short* rb   = (unsigned short*)alloc((size_t)Mc * Dc * 2);
  unsigned short* wqkv = (unsigned short*)alloc((size_t)(NQc + 2 * NKVc) * Dc * 2); // [Q;K;V] rows
  unsigned short* wob  = (unsigned short*)alloc((size_t)Dc * NQc * 2);
  unsigned short* qb   = (unsigned short*)alloc((size_t)Mc * NQc * 2);
  unsigned short* kb   = (unsigned short*)alloc((size_t)Mc * NKVc * 2);
  unsigned short* vbT  = (unsigned short*)alloc((size_t)Mc * NKVc * 2);
  float2* tab          = (float2*)alloc((size_t)Sc * 64 * sizeof(float2));  // 1 MB
  (void)ws_size; (void)in_sizes; (void)n_in; (void)out_size;

  // one fused converter launch (+ RoPE table); W_K/W_V land after W_Q rows
  cvt_all<<<15872, 256, 0, stream>>>(residual, W_Q, W_K, W_V, W_O,
                                     rb, wqkv, wqkv + (size_t)NQc * Dc, wob,
                                     tab, start_pos);

  // fused QKV projection: N = 2048(Q) + 512(K) + 512(V) = 3072
  gemm2b<1><<<dim3(32, 24), 256, 0, stream>>>(rb, wqkv, kf, vf, qb, vbT,
                                              NQc + 2 * NKVc, Dc);

  // fused RoPE (q + k), table-driven
  rope_all<<<5120, 256, 0, stream>>>(qb, kf, kb, tab);

  flash_attn<<<512, 256, 0, stream>>>(qb, kb, vbT, start_pos);

  // output projection: attn (in qb) x W_O^T -> d_out
  gemm2b<0><<<dim3(32, 16), 256, 0, stream>>>(qb, wob, out, nullptr, nullptr,
                                              nullptr, Dc, Dc);
}